// Round 21
// baseline (114.514 us; speedup 1.0000x reference)
//
#include <hip/hip_runtime.h>
#include <math.h>

#define BS        4
#define NQ        300
#define NK        17
#define LEN_Q     5100          // NQ*NK
#define N_HEADS   8
#define N_LEVELS  4
#define N_POINTS  4
#define D_MODEL   256
#define HD        32            // D_MODEL / N_HEADS

// workspace layout (all 16B-aligned):
// vt   : ushort[22282240]               (44.6 MB, transposed bf16 values)
// Qb   : ushort[5222400]  @ vt+VT_TOTAL (10.4 MB, bf16 query)
// Wb   : ushort[98304]    after Qb      (0.2 MB, bf16 [Woff;Wattn])
#define LB0 0
#define LB1 16777216
#define LB2 20971520
#define LB3 22020096
#define VT_TOTAL 22282240
#define QB_N     5222400

#define NTRANS 21760            // 680 x 32 transpose tiles
#define NCVT   2598             // cvt blocks

typedef __attribute__((ext_vector_type(8))) short bf16x8;
typedef __attribute__((ext_vector_type(8))) unsigned short ushort8_t;
typedef __attribute__((ext_vector_type(4))) float f32x4;
typedef __attribute__((ext_vector_type(4))) unsigned int u32x4;

// ---------------------------------------------------------------------------
// bf16 helpers (RNE)
// ---------------------------------------------------------------------------
__device__ __forceinline__ unsigned short f2bf(float x) {
    unsigned u = __float_as_uint(x);
    unsigned r = (u + 0x7fffu + ((u >> 16) & 1u)) >> 16;
    return (unsigned short)r;
}
__device__ __forceinline__ float bf2f(unsigned short s) {
    return __uint_as_float((unsigned)s << 16);
}
// dot2 of packed bf16 pairs: r = v.lo*w.lo + v.hi*w.hi + acc  (VOP3P)
__device__ __forceinline__ float dot2bf(unsigned v, unsigned w, float acc) {
    float r;
    asm("v_dot2_f32_bf16 %0, %1, %2, %3" : "=v"(r) : "v"(v), "v"(w), "v"(acc));
    return r;
}

// ---------------------------------------------------------------------------
// fused streaming prep: blocks [0,21760) = value transpose tiles;
// [21760, 21760+2598) = Q/W fp32->bf16 conversion (homogeneous streamers).
// ---------------------------------------------------------------------------
__global__ __launch_bounds__(256) void prep_kernel(
    const float* __restrict__ v0, const float* __restrict__ v1,
    const float* __restrict__ v2, const float* __restrict__ v3,
    const float* __restrict__ Q, const float* __restrict__ Woff,
    const float* __restrict__ Wattn,
    unsigned short* __restrict__ vt,
    unsigned short* __restrict__ Qb, unsigned short* __restrict__ Wb)
{
    __shared__ float t[32][36];
    int bid = blockIdx.x;
    int tid = threadIdx.x;

    if (bid < NTRANS) {
        // ---- transpose tile: (n, 32, S) fp32 -> (n, S, 32) bf16
        int bx = bid % 680;
        int n  = bid / 680;
        const float* in; int S; size_t ob; int tile;
        if (bx < 512)      { in = v0; S = 16384; ob = LB0; tile = bx; }
        else if (bx < 640) { in = v1; S = 4096;  ob = LB1; tile = bx - 512; }
        else if (bx < 672) { in = v2; S = 1024;  ob = LB2; tile = bx - 640; }
        else               { in = v3; S = 256;   ob = LB3; tile = bx - 672; }

        int s0 = tile * 32;
        int c  = tid >> 3;
        int c4 = (tid & 7) * 4;
        const float* pin = in + (size_t)n * 32 * S;
        *(float4*)&t[c][c4] = *(const float4*)(pin + (size_t)c * S + s0 + c4);
        __syncthreads();

        unsigned short* pout = vt + ob + (size_t)n * S * 32;
        int r = tid >> 3;
        ushort4 w;
        w.x = f2bf(t[c4 + 0][r]);
        w.y = f2bf(t[c4 + 1][r]);
        w.z = f2bf(t[c4 + 2][r]);
        w.w = f2bf(t[c4 + 3][r]);
        *(ushort4*)(pout + (size_t)(s0 + r) * 32 + c4) = w;
    } else {
        // ---- fp32 -> bf16 conversion of Q and [Woff;Wattn]
        int gid = (bid - NTRANS) * 256 + tid;
        const float* src;
        unsigned short* dst;
        size_t off;
        if (gid < 652800) {                   // Q: 5222400 elems / 8
            src = Q; dst = Qb; off = (size_t)gid * 8;
        } else {
            int wg = gid - 652800;            // 0..12287
            off = (size_t)wg * 8;
            dst = Wb;
            if (off < 65536) { src = Woff; }
            else             { src = Wattn; src -= 65536; }
        }
        float4 a = *(const float4*)(src + off);
        float4 b = *(const float4*)(src + off + 4);
        ushort8_t r;
        r[0] = f2bf(a.x); r[1] = f2bf(a.y); r[2] = f2bf(a.z); r[3] = f2bf(a.w);
        r[4] = f2bf(b.x); r[5] = f2bf(b.y); r[6] = f2bf(b.z); r[7] = f2bf(b.w);
        *(ushort8_t*)(dst + off) = r;
    }
}

// ---------------------------------------------------------------------------
// FUSED sampling + per-block proj slice. block = (h, b, 16 q), bid&7 = h.
// phase 0: waves 0-2 each compute one 16x16 MFMA col-tile of this block's
//   proj slice {h*32, h*32+16, 256+h*16} (8 k-steps) -> s_proj[16][52]+bias.
//   NO cross-h redundancy: (qc,b,h) grid partitions proj cols by h.
// phase 1: shuffle softmax + corners from s_proj; s_iw row idx0..3,wpkA,wpkB.
// phase 2: 16 forced-concurrent gathers + perm/dot2 + shfl_xor reduction.
// ---------------------------------------------------------------------------
#define GLD(dst, base, off)                                                  \
    { const unsigned short* _p = (base) + (off);                             \
      asm volatile("global_load_dwordx4 %0, %1, off"                         \
                   : "=v"(dst) : "v"(_p)); }

#define DOT2P(C0, C1, wpk)                                                   \
  a0 = dot2bf(__builtin_amdgcn_perm(C1[0], C0[0], 0x05040100u), wpk, a0);    \
  a1 = dot2bf(__builtin_amdgcn_perm(C1[0], C0[0], 0x07060302u), wpk, a1);    \
  a2 = dot2bf(__builtin_amdgcn_perm(C1[1], C0[1], 0x05040100u), wpk, a2);    \
  a3 = dot2bf(__builtin_amdgcn_perm(C1[1], C0[1], 0x07060302u), wpk, a3);    \
  a4 = dot2bf(__builtin_amdgcn_perm(C1[2], C0[2], 0x05040100u), wpk, a4);    \
  a5 = dot2bf(__builtin_amdgcn_perm(C1[2], C0[2], 0x07060302u), wpk, a5);    \
  a6 = dot2bf(__builtin_amdgcn_perm(C1[3], C0[3], 0x05040100u), wpk, a6);    \
  a7 = dot2bf(__builtin_amdgcn_perm(C1[3], C0[3], 0x07060302u), wpk, a7);

#define RED(v) { v += __shfl_xor(v, 4); v += __shfl_xor(v, 8); }

__global__ __launch_bounds__(256, 4) void ms_deform_kernel(
    const float* __restrict__ rp,            // (BS, NQ, L, NK, 2)
    const unsigned short* __restrict__ Qb,   // bf16 query (M,256)
    const unsigned short* __restrict__ Wb,   // bf16 [Woff;Wattn] (384,256)
    const float* __restrict__ boff, const float* __restrict__ battn,
    const unsigned short* __restrict__ vt,   // transposed bf16 values
    float* __restrict__ out)                 // (BS, LEN_Q, 256)
{
    int bid = blockIdx.x;
    int h   = bid & 7;            // XCD id under round-robin dispatch
    int b   = (bid >> 3) & 3;
    int qc  = bid >> 5;           // 0..318
    int q0  = qc * 16;

    __shared__ int   s_iw[3104];             // 8 groups x 388 dwords (12.5KB)
    __shared__ float s_proj[16][52];         // [q][0..31 off | 32..47 logit]

    int tid = threadIdx.x;

    // ---- phase 0: proj slice via MFMA (waves 0-2), cols {off0,off1,logit}
    {
        int wave = tid >> 6;
        int lane = tid & 63;
        if (wave < 3) {
            int tbase = (wave == 0) ? h * 32
                      : (wave == 1) ? h * 32 + 16
                                    : 256 + h * 16;
            int lr = lane & 15;
            int lk = (lane >> 4) * 8;
            int qrow = q0 + lr; qrow = qrow < LEN_Q ? qrow : LEN_Q - 1;
            const unsigned short* qa = Qb + ((size_t)b * LEN_Q + qrow) * 256 + lk;
            const unsigned short* wb = Wb + (size_t)(tbase + lr) * 256 + lk;
            f32x4 acc = {};
            #pragma unroll
            for (int k0 = 0; k0 < 256; k0 += 32) {
                bf16x8 af = *(const bf16x8*)(qa + k0);
                bf16x8 bf = *(const bf16x8*)(wb + k0);
                acc = __builtin_amdgcn_mfma_f32_16x16x32_bf16(af, bf, acc, 0, 0, 0);
            }
            int col = lane & 15;
            int ncol = tbase + col;
            float bias = (ncol < 256) ? boff[ncol] : battn[ncol - 256];
            int lcol = wave * 16 + col;
            int rb2 = (lane >> 4) * 4;
            #pragma unroll
            for (int r = 0; r < 4; ++r)
                s_proj[rb2 + r][lcol] = acc[r] + bias;
        }
    }
    __syncthreads();

    // ---- phase 1: element (q = tid>>4, lp = tid&15)
    {
        int qL = tid >> 4;
        int lp = tid & 15;
        int l  = lp >> 2;
        int p  = lp & 3;
        int q  = q0 + qL;
        int qq = q < LEN_Q ? q : LEN_Q - 1;

        float g = s_proj[qL][32 + lp];
        float mx = g;
        mx = fmaxf(mx, __shfl_xor(mx, 1, 16));
        mx = fmaxf(mx, __shfl_xor(mx, 2, 16));
        mx = fmaxf(mx, __shfl_xor(mx, 4, 16));
        mx = fmaxf(mx, __shfl_xor(mx, 8, 16));
        float e = __expf(g - mx);
        float s = e;
        s += __shfl_xor(s, 1, 16);
        s += __shfl_xor(s, 2, 16);
        s += __shfl_xor(s, 4, 16);
        s += __shfl_xor(s, 8, 16);
        float a = (q < LEN_Q) ? (e / s) : 0.f;

        int Wl = 128 >> l;            // square levels: 128,64,32,16
        float ww = (float)Wl;
        int qi = qq / NK;
        int ki = qq - qi * NK;
        size_t rbase = ((((size_t)b * NQ + qi) * N_LEVELS + l) * NK + ki) * 2;
        float rx = rp[rbase + 0];
        float ry = rp[rbase + 1];
        float ox = s_proj[qL][lp * 2];
        float oy = s_proj[qL][lp * 2 + 1];
        // grid_sample align_corners=False: x = loc*w - 0.5
        float x = (rx + ox / ww) * ww - 0.5f;
        float y = (ry + oy / ww) * ww - 0.5f;
        float x0f = floorf(x), y0f = floorf(y);
        float wx1 = x - x0f, wy1 = y - y0f;
        float wx0 = 1.f - wx1, wy0 = 1.f - wy1;
        int x0 = (int)x0f, y0 = (int)y0f;

        int idx[4]; float wf[4];
        #pragma unroll
        for (int corner = 0; corner < 4; ++corner) {
            int xi = x0 + (corner & 1);
            int yi = y0 + (corner >> 1);
            float wgt = ((corner & 1) ? wx1 : wx0) * ((corner >> 1) ? wy1 : wy0);
            bool valid = (xi >= 0) && (xi < Wl) && (yi >= 0) && (yi < Wl);
            idx[corner] = valid ? (yi * Wl + xi) * HD : 0;   // ushort-unit idx
            wf[corner]  = valid ? wgt * a : 0.f;
        }
        int* wrow = s_iw + (qL >> 1) * 388 + (p * 8 + l * 2 + (qL & 1)) * 12;
        *(int4*)wrow = make_int4(idx[0], idx[1], idx[2], idx[3]);
        unsigned wpkA = ((unsigned)f2bf(wf[1]) << 16) | f2bf(wf[0]);
        unsigned wpkB = ((unsigned)f2bf(wf[3]) << 16) | f2bf(wf[2]);
        *(int2*)(wrow + 4) = make_int2((int)wpkA, (int)wpkB);
    }
    // phase-1 producers and phase-2 consumers of s_iw are the SAME wave.
    __builtin_amdgcn_wave_barrier();

    // ---- phase 2: tid = qL*16 + l*4 + c8
    int qL = tid >> 4;
    int l  = (tid >> 2) & 3;
    int c8 = tid & 3;
    int n  = b * N_HEADS + h;
    const size_t lb[4]  = {LB0, LB1, LB2, LB3};
    const int    Ssz[4] = {16384, 4096, 1024, 256};

    const unsigned short* vbase = vt + lb[l] + (size_t)n * Ssz[l] * HD + c8 * 8;
    const int* rrow0 = s_iw + (qL >> 1) * 388 + (l * 2 + (qL & 1)) * 12;

    int4 I0 = *(const int4*)(rrow0 + 0);
    int2 W0 = *(const int2*)(rrow0 + 4);
    int4 I1 = *(const int4*)(rrow0 + 96);
    int2 W1 = *(const int2*)(rrow0 + 100);
    int4 I2 = *(const int4*)(rrow0 + 192);
    int2 W2 = *(const int2*)(rrow0 + 196);
    int4 I3 = *(const int4*)(rrow0 + 288);
    int2 W3 = *(const int2*)(rrow0 + 292);

    // 16 gathers, forced concurrent via distinct asm outputs
    u32x4 u00, u01, u02, u03, u10, u11, u12, u13;
    u32x4 u20, u21, u22, u23, u30, u31, u32, u33;
    GLD(u00, vbase, I0.x) GLD(u01, vbase, I0.y)
    GLD(u02, vbase, I0.z) GLD(u03, vbase, I0.w)
    GLD(u10, vbase, I1.x) GLD(u11, vbase, I1.y)
    GLD(u12, vbase, I1.z) GLD(u13, vbase, I1.w)
    GLD(u20, vbase, I2.x) GLD(u21, vbase, I2.y)
    GLD(u22, vbase, I2.z) GLD(u23, vbase, I2.w)
    GLD(u30, vbase, I3.x) GLD(u31, vbase, I3.y)
    GLD(u32, vbase, I3.z) GLD(u33, vbase, I3.w)
    asm volatile("s_waitcnt vmcnt(0)"
        : "+v"(u00), "+v"(u01), "+v"(u02), "+v"(u03),
          "+v"(u10), "+v"(u11), "+v"(u12), "+v"(u13),
          "+v"(u20), "+v"(u21), "+v"(u22), "+v"(u23),
          "+v"(u30), "+v"(u31), "+v"(u32), "+v"(u33));
    __builtin_amdgcn_sched_barrier(0);

    float a0 = 0.f, a1 = 0.f, a2 = 0.f, a3 = 0.f;
    float a4 = 0.f, a5 = 0.f, a6 = 0.f, a7 = 0.f;
    DOT2P(u00, u01, ((unsigned)W0.x))
    DOT2P(u02, u03, ((unsigned)W0.y))
    DOT2P(u10, u11, ((unsigned)W1.x))
    DOT2P(u12, u13, ((unsigned)W1.y))
    DOT2P(u20, u21, ((unsigned)W2.x))
    DOT2P(u22, u23, ((unsigned)W2.y))
    DOT2P(u30, u31, ((unsigned)W3.x))
    DOT2P(u32, u33, ((unsigned)W3.y))

    // reduce over l (lane bits 2-3) in-wave; no LDS, no barrier
    RED(a0) RED(a1) RED(a2) RED(a3) RED(a4) RED(a5) RED(a6) RED(a7)

    if ((tid & 12) == 0) {
        int q = q0 + qL;
        if (q < LEN_Q) {
            float* po = out + (size_t)(b * LEN_Q + q) * 256 + h * 32 + c8 * 8;
            float4 oA = make_float4(a0, a1, a2, a3);
            float4 oB = make_float4(a4, a5, a6, a7);
            *(float4*)po = oA;
            *(float4*)(po + 4) = oB;
        }
    }
}

// ---------------------------------------------------------------------------
extern "C" void kernel_launch(void* const* d_in, const int* in_sizes, int n_in,
                              void* d_out, int out_size, void* d_ws, size_t ws_size,
                              hipStream_t stream)
{
    const float* query = (const float*)d_in[0];
    const float* refp  = (const float*)d_in[1];
    const float* v0    = (const float*)d_in[2];
    const float* v1    = (const float*)d_in[3];
    const float* v2    = (const float*)d_in[4];
    const float* v3    = (const float*)d_in[5];
    const float* Woff  = (const float*)d_in[6];
    const float* boff  = (const float*)d_in[7];
    const float* Wattn = (const float*)d_in[8];
    const float* battn = (const float*)d_in[9];
    float* out = (float*)d_out;
    unsigned short* vt = (unsigned short*)d_ws;
    unsigned short* Qb = vt + VT_TOTAL;
    unsigned short* Wb = Qb + QB_N;

    // 1) fused streaming prep: value transpose + Q/W bf16 conversion
    prep_kernel<<<NTRANS + NCVT, 256, 0, stream>>>(
        v0, v1, v2, v3, query, Woff, Wattn, vt, Qb, Wb);

    // 2) fused proj-slice + sampling: (319 qc) x (4 b) x (8 h); bid%8=h -> XCD
    ms_deform_kernel<<<319 * 32, 256, 0, stream>>>(
        refp, Qb, Wb, boff, battn, vt, out);
}

// Round 22
// 106.300 us; speedup vs baseline: 1.0773x; 1.0773x over previous
//
#include <hip/hip_runtime.h>
#include <math.h>

#define BS        4
#define NQ        300
#define NK        17
#define LEN_Q     5100          // NQ*NK
#define N_HEADS   8
#define N_LEVELS  4
#define N_POINTS  4
#define D_MODEL   256
#define HD        32            // D_MODEL / N_HEADS

// workspace layout (all 16B-aligned):
// vt   : ushort[22282240]              (44.6 MB, transposed bf16 values)
// proj : float [7833600]  @ vt+VT_TOTAL (31.3 MB)
// Qb   : ushort[5222400]  after proj    (10.4 MB, bf16 query)
// Wb   : ushort[98304]    after Qb      (0.2 MB, bf16 [Woff;Wattn])
#define LB0 0
#define LB1 16777216
#define LB2 20971520
#define LB3 22020096
#define VT_TOTAL 22282240
#define PROJ_F32 7833600
#define QB_N     5222400

#define NTRANS 21760            // 680 x 32 transpose tiles
#define NCVT   2598             // cvt blocks

typedef __attribute__((ext_vector_type(8))) short bf16x8;
typedef __attribute__((ext_vector_type(8))) unsigned short ushort8_t;
typedef __attribute__((ext_vector_type(4))) float f32x4;
typedef __attribute__((ext_vector_type(4))) unsigned int u32x4;

// ---------------------------------------------------------------------------
// bf16 helpers (RNE)
// ---------------------------------------------------------------------------
__device__ __forceinline__ unsigned short f2bf(float x) {
    unsigned u = __float_as_uint(x);
    unsigned r = (u + 0x7fffu + ((u >> 16) & 1u)) >> 16;
    return (unsigned short)r;
}
__device__ __forceinline__ float bf2f(unsigned short s) {
    return __uint_as_float((unsigned)s << 16);
}
// dot2 of packed bf16 pairs: r = v.lo*w.lo + v.hi*w.hi + acc  (VOP3P)
__device__ __forceinline__ float dot2bf(unsigned v, unsigned w, float acc) {
    float r;
    asm("v_dot2_f32_bf16 %0, %1, %2, %3" : "=v"(r) : "v"(v), "v"(w), "v"(acc));
    return r;
}

// ---------------------------------------------------------------------------
// fused streaming prep: blocks [0,21760) = value transpose tiles;
// [21760, 21760+2598) = Q/W fp32->bf16 conversion (homogeneous streamers).
// ---------------------------------------------------------------------------
__global__ __launch_bounds__(256) void prep_kernel(
    const float* __restrict__ v0, const float* __restrict__ v1,
    const float* __restrict__ v2, const float* __restrict__ v3,
    const float* __restrict__ Q, const float* __restrict__ Woff,
    const float* __restrict__ Wattn,
    unsigned short* __restrict__ vt,
    unsigned short* __restrict__ Qb, unsigned short* __restrict__ Wb)
{
    __shared__ float t[32][36];
    int bid = blockIdx.x;
    int tid = threadIdx.x;

    if (bid < NTRANS) {
        // ---- transpose tile: (n, 32, S) fp32 -> (n, S, 32) bf16
        int bx = bid % 680;
        int n  = bid / 680;
        const float* in; int S; size_t ob; int tile;
        if (bx < 512)      { in = v0; S = 16384; ob = LB0; tile = bx; }
        else if (bx < 640) { in = v1; S = 4096;  ob = LB1; tile = bx - 512; }
        else if (bx < 672) { in = v2; S = 1024;  ob = LB2; tile = bx - 640; }
        else               { in = v3; S = 256;   ob = LB3; tile = bx - 672; }

        int s0 = tile * 32;
        int c  = tid >> 3;
        int c4 = (tid & 7) * 4;
        const float* pin = in + (size_t)n * 32 * S;
        *(float4*)&t[c][c4] = *(const float4*)(pin + (size_t)c * S + s0 + c4);
        __syncthreads();

        unsigned short* pout = vt + ob + (size_t)n * S * 32;
        int r = tid >> 3;
        ushort4 w;
        w.x = f2bf(t[c4 + 0][r]);
        w.y = f2bf(t[c4 + 1][r]);
        w.z = f2bf(t[c4 + 2][r]);
        w.w = f2bf(t[c4 + 3][r]);
        *(ushort4*)(pout + (size_t)(s0 + r) * 32 + c4) = w;
    } else {
        // ---- fp32 -> bf16 conversion of Q and [Woff;Wattn]
        int gid = (bid - NTRANS) * 256 + tid;
        const float* src;
        unsigned short* dst;
        size_t off;
        if (gid < 652800) {                   // Q: 5222400 elems / 8
            src = Q; dst = Qb; off = (size_t)gid * 8;
        } else {
            int wg = gid - 652800;            // 0..12287
            off = (size_t)wg * 8;
            dst = Wb;
            if (off < 65536) { src = Woff; }
            else             { src = Wattn; src -= 65536; }
        }
        float4 a = *(const float4*)(src + off);
        float4 b = *(const float4*)(src + off + 4);
        ushort8_t r;
        r[0] = f2bf(a.x); r[1] = f2bf(a.y); r[2] = f2bf(a.z); r[3] = f2bf(a.w);
        r[4] = f2bf(b.x); r[5] = f2bf(b.y); r[6] = f2bf(b.z); r[7] = f2bf(b.w);
        *(ushort8_t*)(dst + off) = r;
    }
}

// ---------------------------------------------------------------------------
// MFMA proj GEMM v4 (proven): bf16 inputs, 4 loads + 4 MFMA per k-step.
// BM=64 x BN=64, 4 waves, grid (6, 319) = 1914 blocks.
// ---------------------------------------------------------------------------
__global__ __launch_bounds__(256) void proj_gemm_mfma(
    const unsigned short* __restrict__ Qb,
    const unsigned short* __restrict__ Wb,
    const float* __restrict__ boff, const float* __restrict__ battn,
    float* __restrict__ P, int M)
{
    int tid  = threadIdx.x;
    int wave = tid >> 6;
    int lane = tid & 63;
    int bm = blockIdx.y * 64;           // 319 row-blocks
    int bn = blockIdx.x * 64;           // 6 col-blocks (n fastest: Q L2 reuse)
    int wm = (wave & 1) * 32;
    int wn = (wave >> 1) * 32;
    int lr = lane & 15;
    int lk = (lane >> 4) * 8;

    int ra0 = bm + wm + lr;       ra0 = ra0 < M ? ra0 : M - 1;
    int ra1 = bm + wm + 16 + lr;  ra1 = ra1 < M ? ra1 : M - 1;
    const unsigned short* qa0 = Qb + (size_t)ra0 * 256 + lk;
    const unsigned short* qa1 = Qb + (size_t)ra1 * 256 + lk;
    const unsigned short* wb0 = Wb + (size_t)(bn + wn + lr) * 256 + lk;
    const unsigned short* wb1 = Wb + (size_t)(bn + wn + 16 + lr) * 256 + lk;

    f32x4 acc[2][2] = {};
    #pragma unroll
    for (int k0 = 0; k0 < 256; k0 += 32) {
        bf16x8 a0 = *(const bf16x8*)(qa0 + k0);
        bf16x8 a1 = *(const bf16x8*)(qa1 + k0);
        bf16x8 b0 = *(const bf16x8*)(wb0 + k0);
        bf16x8 b1 = *(const bf16x8*)(wb1 + k0);
        acc[0][0] = __builtin_amdgcn_mfma_f32_16x16x32_bf16(a0, b0, acc[0][0], 0, 0, 0);
        acc[0][1] = __builtin_amdgcn_mfma_f32_16x16x32_bf16(a0, b1, acc[0][1], 0, 0, 0);
        acc[1][0] = __builtin_amdgcn_mfma_f32_16x16x32_bf16(a1, b0, acc[1][0], 0, 0, 0);
        acc[1][1] = __builtin_amdgcn_mfma_f32_16x16x32_bf16(a1, b1, acc[1][1], 0, 0, 0);
    }

    #pragma unroll
    for (int i = 0; i < 2; ++i) {
        int mbase = bm + wm + i * 16 + (lane >> 4) * 4;
        #pragma unroll
        for (int j = 0; j < 2; ++j) {
            int n = bn + wn + j * 16 + (lane & 15);
            float bias = (n < 256) ? boff[n] : battn[n - 256];
            #pragma unroll
            for (int r = 0; r < 4; ++r) {
                int row = mbase + r;
                if (row < M) P[(size_t)row * 384 + n] = acc[i][j][r] + bias;
            }
        }
    }
}

// ---------------------------------------------------------------------------
// sampling: head-partitioned (bid&7 = h -> XCD h), block = (h, b, 16 q).
// Phase-1/2 are wave-local (wave_barrier only). s_iw row: idx0..3,wpkA,wpkB.
// phase 2: 16 gathers via inline-asm global_load_dwordx4 (distinct "=v"
// outputs + one vmcnt(0) carrying all 16) + perm/dot2 + shfl_xor reduction.
// ---------------------------------------------------------------------------
#define GLD(dst, base, off)                                                  \
    { const unsigned short* _p = (base) + (off);                             \
      asm volatile("global_load_dwordx4 %0, %1, off"                         \
                   : "=v"(dst) : "v"(_p)); }

#define DOT2P(C0, C1, wpk)                                                   \
  a0 = dot2bf(__builtin_amdgcn_perm(C1[0], C0[0], 0x05040100u), wpk, a0);    \
  a1 = dot2bf(__builtin_amdgcn_perm(C1[0], C0[0], 0x07060302u), wpk, a1);    \
  a2 = dot2bf(__builtin_amdgcn_perm(C1[1], C0[1], 0x05040100u), wpk, a2);    \
  a3 = dot2bf(__builtin_amdgcn_perm(C1[1], C0[1], 0x07060302u), wpk, a3);    \
  a4 = dot2bf(__builtin_amdgcn_perm(C1[2], C0[2], 0x05040100u), wpk, a4);    \
  a5 = dot2bf(__builtin_amdgcn_perm(C1[2], C0[2], 0x07060302u), wpk, a5);    \
  a6 = dot2bf(__builtin_amdgcn_perm(C1[3], C0[3], 0x05040100u), wpk, a6);    \
  a7 = dot2bf(__builtin_amdgcn_perm(C1[3], C0[3], 0x07060302u), wpk, a7);

#define RED(v) { v += __shfl_xor(v, 4); v += __shfl_xor(v, 8); }

__global__ __launch_bounds__(256, 4) void ms_deform_kernel(
    const float* __restrict__ rp,            // (BS, NQ, L, NK, 2)
    const float* __restrict__ proj,          // (BS*LEN_Q, 384)
    const unsigned short* __restrict__ vt,   // transposed bf16 values
    float* __restrict__ out)                 // (BS, LEN_Q, 256)
{
    int bid = blockIdx.x;
    int h   = bid & 7;            // XCD id under round-robin dispatch
    int b   = (bid >> 3) & 3;
    int qc  = bid >> 5;           // 0..318
    int q0  = qc * 16;

    __shared__ int s_iw[3104];               // 8 groups x 388 dwords (12.5KB)

    int tid = threadIdx.x;

    // phase 1: element (q = tid>>4, lp = tid&15)
    {
        int qL = tid >> 4;
        int lp = tid & 15;
        int l  = lp >> 2;
        int p  = lp & 3;
        int q  = q0 + qL;
        int qq = q < LEN_Q ? q : LEN_Q - 1;
        const float* prow = proj + (size_t)(b * LEN_Q + qq) * 384;

        float g = prow[256 + h * 16 + lp];
        float mx = g;
        mx = fmaxf(mx, __shfl_xor(mx, 1, 16));
        mx = fmaxf(mx, __shfl_xor(mx, 2, 16));
        mx = fmaxf(mx, __shfl_xor(mx, 4, 16));
        mx = fmaxf(mx, __shfl_xor(mx, 8, 16));
        float e = __expf(g - mx);
        float s = e;
        s += __shfl_xor(s, 1, 16);
        s += __shfl_xor(s, 2, 16);
        s += __shfl_xor(s, 4, 16);
        s += __shfl_xor(s, 8, 16);
        float a = (q < LEN_Q) ? (e / s) : 0.f;

        int Wl = 128 >> l;            // square levels: 128,64,32,16
        float ww = (float)Wl;
        int qi = qq / NK;
        int ki = qq - qi * NK;
        size_t rbase = ((((size_t)b * NQ + qi) * N_LEVELS + l) * NK + ki) * 2;
        float rx = rp[rbase + 0];
        float ry = rp[rbase + 1];
        int oj = (h * 16 + lp) * 2;
        float ox = prow[oj], oy = prow[oj + 1];
        // grid_sample align_corners=False: x = loc*w - 0.5
        float x = (rx + ox / ww) * ww - 0.5f;
        float y = (ry + oy / ww) * ww - 0.5f;
        float x0f = floorf(x), y0f = floorf(y);
        float wx1 = x - x0f, wy1 = y - y0f;
        float wx0 = 1.f - wx1, wy0 = 1.f - wy1;
        int x0 = (int)x0f, y0 = (int)y0f;

        int idx[4]; float wf[4];
        #pragma unroll
        for (int corner = 0; corner < 4; ++corner) {
            int xi = x0 + (corner & 1);
            int yi = y0 + (corner >> 1);
            float wgt = ((corner & 1) ? wx1 : wx0) * ((corner >> 1) ? wy1 : wy0);
            bool valid = (xi >= 0) && (xi < Wl) && (yi >= 0) && (yi < Wl);
            idx[corner] = valid ? (yi * Wl + xi) * HD : 0;   // ushort-unit idx
            wf[corner]  = valid ? wgt * a : 0.f;
        }
        int* wrow = s_iw + (qL >> 1) * 388 + (p * 8 + l * 2 + (qL & 1)) * 12;
        *(int4*)wrow = make_int4(idx[0], idx[1], idx[2], idx[3]);
        unsigned wpkA = ((unsigned)f2bf(wf[1]) << 16) | f2bf(wf[0]);
        unsigned wpkB = ((unsigned)f2bf(wf[3]) << 16) | f2bf(wf[2]);
        *(int2*)(wrow + 4) = make_int2((int)wpkA, (int)wpkB);
    }
    // phase-1 producers and phase-2 consumers are the SAME wave.
    __builtin_amdgcn_wave_barrier();

    // phase 2: tid = qL*16 + l*4 + c8
    int qL = tid >> 4;
    int l  = (tid >> 2) & 3;
    int c8 = tid & 3;
    int n  = b * N_HEADS + h;
    const size_t lb[4]  = {LB0, LB1, LB2, LB3};
    const int    Ssz[4] = {16384, 4096, 1024, 256};

    const unsigned short* vbase = vt + lb[l] + (size_t)n * Ssz[l] * HD + c8 * 8;
    const int* rrow0 = s_iw + (qL >> 1) * 388 + (l * 2 + (qL & 1)) * 12;

    int4 I0 = *(const int4*)(rrow0 + 0);
    int2 W0 = *(const int2*)(rrow0 + 4);
    int4 I1 = *(const int4*)(rrow0 + 96);
    int2 W1 = *(const int2*)(rrow0 + 100);
    int4 I2 = *(const int4*)(rrow0 + 192);
    int2 W2 = *(const int2*)(rrow0 + 196);
    int4 I3 = *(const int4*)(rrow0 + 288);
    int2 W3 = *(const int2*)(rrow0 + 292);

    // 16 gathers, forced concurrent via distinct asm outputs
    u32x4 u00, u01, u02, u03, u10, u11, u12, u13;
    u32x4 u20, u21, u22, u23, u30, u31, u32, u33;
    GLD(u00, vbase, I0.x) GLD(u01, vbase, I0.y)
    GLD(u02, vbase, I0.z) GLD(u03, vbase, I0.w)
    GLD(u10, vbase, I1.x) GLD(u11, vbase, I1.y)
    GLD(u12, vbase, I1.z) GLD(u13, vbase, I1.w)
    GLD(u20, vbase, I2.x) GLD(u21, vbase, I2.y)
    GLD(u22, vbase, I2.z) GLD(u23, vbase, I2.w)
    GLD(u30, vbase, I3.x) GLD(u31, vbase, I3.y)
    GLD(u32, vbase, I3.z) GLD(u33, vbase, I3.w)
    asm volatile("s_waitcnt vmcnt(0)"
        : "+v"(u00), "+v"(u01), "+v"(u02), "+v"(u03),
          "+v"(u10), "+v"(u11), "+v"(u12), "+v"(u13),
          "+v"(u20), "+v"(u21), "+v"(u22), "+v"(u23),
          "+v"(u30), "+v"(u31), "+v"(u32), "+v"(u33));
    __builtin_amdgcn_sched_barrier(0);

    float a0 = 0.f, a1 = 0.f, a2 = 0.f, a3 = 0.f;
    float a4 = 0.f, a5 = 0.f, a6 = 0.f, a7 = 0.f;
    DOT2P(u00, u01, ((unsigned)W0.x))
    DOT2P(u02, u03, ((unsigned)W0.y))
    DOT2P(u10, u11, ((unsigned)W1.x))
    DOT2P(u12, u13, ((unsigned)W1.y))
    DOT2P(u20, u21, ((unsigned)W2.x))
    DOT2P(u22, u23, ((unsigned)W2.y))
    DOT2P(u30, u31, ((unsigned)W3.x))
    DOT2P(u32, u33, ((unsigned)W3.y))

    // reduce over l (lane bits 2-3) in-wave; no LDS, no barrier
    RED(a0) RED(a1) RED(a2) RED(a3) RED(a4) RED(a5) RED(a6) RED(a7)

    if ((tid & 12) == 0) {
        int q = q0 + qL;
        if (q < LEN_Q) {
            float* po = out + (size_t)(b * LEN_Q + q) * 256 + h * 32 + c8 * 8;
            float4 oA = make_float4(a0, a1, a2, a3);
            float4 oB = make_float4(a4, a5, a6, a7);
            *(float4*)po = oA;
            *(float4*)(po + 4) = oB;
        }
    }
}

// ---------------------------------------------------------------------------
extern "C" void kernel_launch(void* const* d_in, const int* in_sizes, int n_in,
                              void* d_out, int out_size, void* d_ws, size_t ws_size,
                              hipStream_t stream)
{
    const float* query = (const float*)d_in[0];
    const float* refp  = (const float*)d_in[1];
    const float* v0    = (const float*)d_in[2];
    const float* v1    = (const float*)d_in[3];
    const float* v2    = (const float*)d_in[4];
    const float* v3    = (const float*)d_in[5];
    const float* Woff  = (const float*)d_in[6];
    const float* boff  = (const float*)d_in[7];
    const float* Wattn = (const float*)d_in[8];
    const float* battn = (const float*)d_in[9];
    float* out = (float*)d_out;
    unsigned short* vt = (unsigned short*)d_ws;
    float* proj = (float*)(vt + VT_TOTAL);
    unsigned short* Qb = (unsigned short*)(proj + PROJ_F32);
    unsigned short* Wb = Qb + QB_N;

    int M = BS * LEN_Q;                       // 20400

    // 1) fused streaming prep: value transpose + Q/W bf16 conversion
    prep_kernel<<<NTRANS + NCVT, 256, 0, stream>>>(
        v0, v1, v2, v3, query, Woff, Wattn, vt, Qb, Wb);

    // 2) proj MFMA GEMM v4 (bf16 inputs) -> (M, 384)
    proj_gemm_mfma<<<dim3(6, (M + 63) / 64), 256, 0, stream>>>(
        Qb, Wb, boff, battn, proj, M);

    // 3) sampling: (319 q-chunks) x (4 b) x (8 h); blockIdx%8 = h -> XCD h
    ms_deform_kernel<<<319 * 32, 256, 0, stream>>>(refp, proj, vt, out);
}